// Round 7
// baseline (938.885 us; speedup 1.0000x reference)
//
#include <hip/hip_runtime.h>
#include <hip/hip_cooperative_groups.h>
#include <hip/hip_bf16.h>
#include <cstdint>

namespace cg = cooperative_groups;

#define BATCH 128
#define SEQ   512
#define EMB   300
#define HID   100
#define G3    300
#define NCLS  20
#define NROWS (SEQ * BATCH)

#define M1_WORDS 614400   // 128*512*300 / 32
#define M2_WORDS 204800   // 512*128*100 / 32

typedef __attribute__((ext_vector_type(4))) float f32x4;
typedef __attribute__((ext_vector_type(8))) short s16x8;
typedef __fp16 h16x2 __attribute__((ext_vector_type(2)));   // matches cvt_pkrtz return

// ---------------- threefry2x32 (JAX-compatible, verified round 1) ----------------
__host__ __device__ __forceinline__ void threefry2x32(uint32_t k0, uint32_t k1,
                                                      uint32_t x0, uint32_t x1,
                                                      uint32_t* o0, uint32_t* o1) {
  uint32_t ks2 = k0 ^ k1 ^ 0x1BD11BDAu;
  x0 += k0; x1 += k1;
#define TFR(r) { x0 += x1; x1 = (x1 << (r)) | (x1 >> (32 - (r))); x1 ^= x0; }
  TFR(13) TFR(15) TFR(26) TFR(6)  x0 += k1;  x1 += ks2 + 1u;
  TFR(17) TFR(29) TFR(16) TFR(24) x0 += ks2; x1 += k0 + 2u;
  TFR(13) TFR(15) TFR(26) TFR(6)  x0 += k0;  x1 += k1 + 3u;
  TFR(17) TFR(29) TFR(16) TFR(24) x0 += k1;  x1 += ks2 + 4u;
  TFR(13) TFR(15) TFR(26) TFR(6)  x0 += ks2; x1 += k0 + 5u;
#undef TFR
  *o0 = x0; *o1 = x1;
}

__device__ __forceinline__ uint32_t rand_bits32(uint32_t ka, uint32_t kb, uint32_t flat) {
  uint32_t a, b;
  threefry2x32(ka, kb, 0u, flat, &a, &b);
  return a ^ b;
}

__device__ __forceinline__ short f2bf(float f) {   // RNE fp32->bf16
  union { float f; uint32_t u; } c; c.f = f;
  uint32_t u = c.u;
  return (short)((u + 0x7FFFu + ((u >> 16) & 1u)) >> 16);
}

// raw barrier: LDS-only drain, no vmcnt(0)
__device__ __forceinline__ void bar_lds() {
  __asm__ __volatile__("s_waitcnt lgkmcnt(0)" ::: "memory");
  __builtin_amdgcn_s_barrier();
  __asm__ __volatile__("" ::: "memory");
}

// lane i <- lane i^4 (BitMode: xor=4, and=0x1F)
__device__ __forceinline__ float swz_xor4(float x) {
  return __builtin_bit_cast(float,
      __builtin_amdgcn_ds_swizzle(__builtin_bit_cast(int, x), 0x101F));
}

// ================= fused pipeline: ONE cooperative dispatch =================
// 256 blocks x 512 threads (2 blocks/CU co-resident; launch_bounds(512,4)).
// Phase A: dropout masks (grid-stride, full chip) + Wb bf16 prep.
// Phase B: GI GEMM (verified gi7 body), s = 2*bid + si, si in {0,1}.
// Phase C: RNN (verified rnn11 body), b = bid < 128 (others wait at sync).
// Phase D: logits + log_softmax, 1 row/thread.
// grid.sync() between phases (4 handshakes total; NOT R5's per-step spin).
__global__ __launch_bounds__(512, 4) void k_all(
    const int* __restrict__ inputs, const float* __restrict__ emb,
    const float* __restrict__ w_ih, const float* __restrict__ w_hh,
    const float* __restrict__ b_ih, const float* __restrict__ b_hh,
    const float* __restrict__ w_lin, const float* __restrict__ b_lin,
    float* __restrict__ out, float* __restrict__ GI, float* __restrict__ Hd,
    uint32_t* __restrict__ M1w, uint32_t* __restrict__ M2w,
    short* __restrict__ Wb,
    uint32_t k1a, uint32_t k1b, uint32_t k2a, uint32_t k2b) {
  __shared__ __align__(16) char smem[35072];   // gi7: As(10240)+Bs(24320)+idxs(512)
  const int t = threadIdx.x, bid = blockIdx.x;
  const int flat = bid * 512 + t;

  // ===================== Phase A: masks + Wb prep =====================
  for (int i = flat; i < M1_WORDS + M2_WORDS; i += 256 * 512) {
    uint32_t ka, kb, base;
    uint32_t* dst;
    if (i < M1_WORDS) { ka = k1a; kb = k1b; base = (uint32_t)i * 32u; dst = M1w + i; }
    else { ka = k2a; kb = k2b; base = (uint32_t)(i - M1_WORDS) * 32u; dst = M2w + (i - M1_WORDS); }
    uint32_t w = 0u;
#pragma unroll
    for (int j = 0; j < 32; ++j) {
      uint32_t bits = rand_bits32(ka, kb, base + (uint32_t)j);
      w |= ((~bits) >> 31) << j;
    }
    *dst = w;
  }
  if (flat < 304 * 320 / 8) {
    const int i8 = flat * 8;
    short o[8];
#pragma unroll
    for (int j = 0; j < 8; ++j) {
      int pos = i8 + j;
      int n = pos / 320, k = pos - (pos / 320) * 320;
      float v = (n < 300 && k < 300) ? w_ih[(size_t)n * EMB + k] : 0.f;
      o[j] = f2bf(v);
    }
    *(s16x8*)(Wb + i8) = *(s16x8*)o;
  }
  __threadfence();
  cg::this_grid().sync();
  __threadfence();

  // ===================== Phase B: GI GEMM (gi7 body) =====================
  {
    short* As = (short*)smem;                  // [128*40]
    short* Bs = As + 128 * 40;                 // [304*40]
    int* idxs = (int*)(Bs + 304 * 40);         // [128]
    const int lane = t & 63, wave = t >> 6;
    const int wr = wave & 1, wc = wave >> 1;
    const int ml = lane & 15, quad = lane >> 4;
    const int arow = t >> 2, akq = t & 3;
    const int nfr = (wc < 3) ? 5 : 4;

    for (int si = 0; si < 2; ++si) {
      const int s = bid * 2 + si;
      __syncthreads();                         // guard As/Bs/idxs vs prev si reads
      if (t < 128) idxs[t] = inputs[t * SEQ + s];
      __syncthreads();

      f32x4 acc[4][5];
#pragma unroll
      for (int i = 0; i < 4; ++i)
#pragma unroll
        for (int j = 0; j < 5; ++j) acc[i][j] = (f32x4){0.f, 0.f, 0.f, 0.f};

      const int myidx = idxs[arow];

      for (int c = 0; c < 10; ++c) {
        const int e0 = c * 32 + akq * 8;
        float xa[8];
#pragma unroll
        for (int j = 0; j < 8; ++j) xa[j] = 0.f;
        if (e0 + 7 < 300) {
#pragma unroll
          for (int q4 = 0; q4 < 2; ++q4) {
            float4 v = *(const float4*)(emb + (size_t)myidx * EMB + e0 + q4 * 4);
            xa[q4 * 4 + 0] = v.x; xa[q4 * 4 + 1] = v.y;
            xa[q4 * 4 + 2] = v.z; xa[q4 * 4 + 3] = v.w;
          }
        } else if (e0 < 300) {
#pragma unroll
          for (int j = 0; j < 8; ++j) {
            int e = e0 + j;
            if (e < 300) xa[j] = emb[(size_t)myidx * EMB + e];
          }
        }
        uint32_t mb = 0;
        if (e0 < 300) {
          uint32_t base = (uint32_t)((arow * SEQ + s) * EMB + e0);
          uint64_t mw = (uint64_t)M1w[base >> 5] | ((uint64_t)M1w[(base >> 5) + 1] << 32);
          mb = (uint32_t)(mw >> (base & 31));
        }
        short sa[8];
#pragma unroll
        for (int j = 0; j < 8; ++j)
          sa[j] = f2bf(((mb >> j) & 1u) ? xa[j] * 2.f : 0.f);
        s16x8 bv0, bv1, bv2;
        {
          int i0 = t;
          bv0 = *(const s16x8*)(Wb + (size_t)(i0 >> 2) * 320 + c * 32 + (i0 & 3) * 8);
          int i1 = t + 512;
          bv1 = *(const s16x8*)(Wb + (size_t)(i1 >> 2) * 320 + c * 32 + (i1 & 3) * 8);
          if (t < 192) {
            int i2 = t + 1024;
            bv2 = *(const s16x8*)(Wb + (size_t)(i2 >> 2) * 320 + c * 32 + (i2 & 3) * 8);
          }
        }
        if (c > 0) __syncthreads();
        *(s16x8*)&As[arow * 40 + akq * 8] = *(s16x8*)&sa[0];
        {
          int i0 = t;       *(s16x8*)&Bs[(i0 >> 2) * 40 + (i0 & 3) * 8] = bv0;
          int i1 = t + 512; *(s16x8*)&Bs[(i1 >> 2) * 40 + (i1 & 3) * 8] = bv1;
          if (t < 192) { int i2 = t + 1024; *(s16x8*)&Bs[(i2 >> 2) * 40 + (i2 & 3) * 8] = bv2; }
        }
        __syncthreads();
        s16x8 af[4];
#pragma unroll
        for (int mt = 0; mt < 4; ++mt)
          af[mt] = *(const s16x8*)&As[(wr * 64 + mt * 16 + ml) * 40 + quad * 8];
#pragma unroll
        for (int j = 0; j < 5; ++j) {
          if (j < nfr) {
            int nt = wc + 4 * j;
            s16x8 bf = *(const s16x8*)&Bs[(nt * 16 + ml) * 40 + quad * 8];
#pragma unroll
            for (int mt = 0; mt < 4; ++mt)
              acc[mt][j] = __builtin_amdgcn_mfma_f32_16x16x32_bf16(af[mt], bf, acc[mt][j], 0, 0, 0);
          }
        }
      }

#pragma unroll
      for (int j = 0; j < 5; ++j) {
        if (j < nfr) {
          int n = (wc + 4 * j) * 16 + ml;
          if (n < 300) {
            float bias = b_ih[n];
#pragma unroll
            for (int mt = 0; mt < 4; ++mt) {
#pragma unroll
              for (int i = 0; i < 4; ++i) {
                int brow = wr * 64 + mt * 16 + quad * 4 + i;
                GI[(size_t)(s * BATCH + brow) * G3 + n] = acc[mt][j][i] + bias;
              }
            }
          }
        }
      }
    }
  }
  __threadfence();
  cg::this_grid().sync();
  __threadfence();

  // ===================== Phase C: RNN (rnn11 body) =====================
  if (bid < BATCH) {
    uint32_t (*hp_s)[64] = (uint32_t (*)[64])smem;   // [2][64]
    const int b = bid;
    const int u = t >> 2, ks = t & 3;
    const bool act = (u < 100);
    const bool gate = act && (ks == 0);
    const int uc = act ? u : 99;
    const int kplo = (ks < 2) ? ks * 13 : 26 + (ks - 2) * 12;
    const int np = (ks < 2) ? 13 : 12;

    const float* rowR = w_hh + (size_t)uc * HID;
    const float* rowZ = w_hh + (size_t)(uc + 100) * HID;
    const float* rowN = w_hh + (size_t)(uc + 200) * HID;
    const h16x2 z2 = (h16x2){(__fp16)0.f, (__fp16)0.f};
    h16x2 wR[13], wZ[13], wN[13];
#pragma unroll
    for (int j = 0; j < 13; ++j) {
      if (j < np) {
        int o = 2 * (kplo + j);
        wR[j] = __builtin_amdgcn_cvt_pkrtz(rowR[o], rowR[o + 1]);
        wZ[j] = __builtin_amdgcn_cvt_pkrtz(rowZ[o], rowZ[o + 1]);
        wN[j] = __builtin_amdgcn_cvt_pkrtz(rowN[o], rowN[o + 1]);
      } else { wR[j] = z2; wZ[j] = z2; wN[j] = z2; }
    }

    float bR0 = 0.f, bZ0 = 0.f, bN0 = 0.f;
    float gcR = 0.f, gcZ = 0.f, gcN = 0.f;
    uint8_t mc = 0;
    const uint8_t* M2 = (const uint8_t*)M2w;
    if (gate) {
      bR0 = b_hh[u]; bZ0 = b_hh[100 + u]; bN0 = b_hh[200 + u];
      const float* g0 = GI + (size_t)b * G3;
      gcR = g0[u]; gcZ = g0[100 + u]; gcN = g0[200 + u];
      mc = M2[(uint32_t)(b * HID + u) >> 3];
    }
    const int p = u >> 1;
    const int sidx = (p < 13) ? 0 : (p < 26) ? 1 : (p < 38) ? 2 : 3;
    const int spos = p - ((sidx < 2) ? sidx * 13 : 26 + (sidx - 2) * 12);
    const int slot = sidx * 16 + spos;
    const bool writer = gate && !(u & 1);

    if (t < 128) ((uint32_t*)hp_s)[t] = 0u;
    float hprev = 0.f;
    __syncthreads();

#define QPX(x, c) __builtin_bit_cast(float, __builtin_amdgcn_mov_dpp( \
    __builtin_bit_cast(int, (x)), (c), 0xF, 0xF, true))
#define DOT1(J, W) { h16x2 hh = __builtin_bit_cast(h16x2, (W)); \
    sR = __builtin_amdgcn_fdot2(wR[J], hh, sR, false); \
    sZ = __builtin_amdgcn_fdot2(wZ[J], hh, sZ, false); \
    sN = __builtin_amdgcn_fdot2(wN[J], hh, sN, false); }

#pragma unroll 2
    for (int s = 0; s < SEQ; ++s) {
      float gnR = 0.f, gnZ = 0.f, gnN = 0.f;
      uint8_t mn = 0;
      if (gate) {
        int sn = (s + 1 < SEQ) ? s + 1 : s;
        const float* gp = GI + (size_t)(sn * BATCH + b) * G3;
        gnR = gp[u]; gnZ = gp[100 + u]; gnN = gp[200 + u];
        mn = M2[(uint32_t)((sn * BATCH + b) * HID + u) >> 3];
      }

      if (act) {
        float sR = bR0, sZ = bZ0, sN = bN0;
        const uint32_t* hb = &hp_s[s & 1][0] + (ks << 4);
        uint4 h0 = *(const uint4*)hb;
        uint4 h1 = *(const uint4*)(hb + 4);
        uint4 h2 = *(const uint4*)(hb + 8);
        uint32_t h3 = hb[12];
        DOT1(0, h0.x)  DOT1(1, h0.y)  DOT1(2, h0.z)  DOT1(3, h0.w)
        DOT1(4, h1.x)  DOT1(5, h1.y)  DOT1(6, h1.z)  DOT1(7, h1.w)
        DOT1(8, h2.x)  DOT1(9, h2.y)  DOT1(10, h2.z) DOT1(11, h2.w)
        DOT1(12, h3)
        sR += QPX(sR, 0xB1); sZ += QPX(sZ, 0xB1); sN += QPX(sN, 0xB1);
        sR += QPX(sR, 0x4E); sZ += QPX(sZ, 0x4E); sN += QPX(sN, 0x4E);
        if (gate) {
          float r = 1.f / (1.f + __expf(-(gcR + sR)));
          float z = 1.f / (1.f + __expf(-(gcZ + sZ)));
          float xn = gcN + r * sN;
          float e2 = __expf(2.f * fabsf(xn));
          float n = copysignf(1.f - 2.f / (e2 + 1.f), xn);
          float hnew = (1.f - z) * n + z * hprev;
          hprev = hnew;
          uint32_t fl = (uint32_t)((s * BATCH + b) * HID + u);
          float hd = ((mc >> (fl & 7)) & 1) ? hnew * 2.f : 0.f;
          Hd[(size_t)(b * SEQ + s) * HID + u] = hd;
          float hoth = swz_xor4(hnew);
          if (writer)
            hp_s[(s & 1) ^ 1][slot] =
                __builtin_bit_cast(uint32_t, __builtin_amdgcn_cvt_pkrtz(hnew, hoth));
        }
      }
      gcR = gnR; gcZ = gnZ; gcN = gnN; mc = mn;
      bar_lds();
    }
#undef DOT1
#undef QPX
  }
  __threadfence();
  cg::this_grid().sync();
  __threadfence();

  // ===================== Phase D: logits + log_softmax =====================
  {
    float* Wl = (float*)smem;          // 2000 floats
    float* bl = Wl + NCLS * HID;       // 20 floats
    __syncthreads();
    for (int i = t; i < NCLS * HID; i += 512) Wl[i] = w_lin[i];
    if (t < NCLS) bl[t] = b_lin[t];
    __syncthreads();
    if (flat < NROWS) {
      const int r = flat, b = r >> 9, s0 = r & 511;
      const float* hrow = Hd + (size_t)r * HID;
      float acc[NCLS];
#pragma unroll
      for (int c = 0; c < NCLS; ++c) acc[c] = bl[c];
      for (int k = 0; k < HID; k += 4) {
        const float4 h = *(const float4*)(hrow + k);
#pragma unroll
        for (int c = 0; c < NCLS; ++c) {
          const float4 w4 = *(const float4*)&Wl[c * HID + k];
          acc[c] += h.x * w4.x + h.y * w4.y + h.z * w4.z + h.w * w4.w;
        }
      }
      float mx = acc[0];
#pragma unroll
      for (int c = 1; c < NCLS; ++c) mx = fmaxf(mx, acc[c]);
      float se = 0.f;
#pragma unroll
      for (int c = 0; c < NCLS; ++c) se += __expf(acc[c] - mx);
      const float lse = mx + __logf(se);
#pragma unroll
      for (int c = 0; c < NCLS; ++c)
        out[(size_t)(b * NCLS + c) * SEQ + s0] = acc[c] - lse;
    }
  }
}

// ================= legacy fallback kernels (R6-verbatim) =================
__global__ __launch_bounds__(256) void k_mask(uint32_t* __restrict__ M1w,
                                              uint32_t* __restrict__ M2w,
                                              uint32_t k1a, uint32_t k1b,
                                              uint32_t k2a, uint32_t k2b) {
  const int i = blockIdx.x * 256 + threadIdx.x;
  uint32_t ka, kb, base;
  uint32_t* dst;
  if (i < M1_WORDS) { ka = k1a; kb = k1b; base = (uint32_t)i * 32u; dst = M1w + i; }
  else { ka = k2a; kb = k2b; base = (uint32_t)(i - M1_WORDS) * 32u; dst = M2w + (i - M1_WORDS); }
  uint32_t w = 0u;
#pragma unroll
  for (int j = 0; j < 32; ++j) {
    uint32_t bits = rand_bits32(ka, kb, base + (uint32_t)j);
    w |= ((~bits) >> 31) << j;
  }
  *dst = w;
}

__global__ __launch_bounds__(256) void k_prepw(const float* __restrict__ w_ih,
                                               short* __restrict__ Wb) {
  int i8 = (blockIdx.x * 256 + threadIdx.x) * 8;
  if (i8 >= 304 * 320) return;
  short o[8];
#pragma unroll
  for (int j = 0; j < 8; ++j) {
    int pos = i8 + j;
    int n = pos / 320, k = pos - (pos / 320) * 320;
    float v = (n < 300 && k < 300) ? w_ih[(size_t)n * EMB + k] : 0.f;
    o[j] = f2bf(v);
  }
  *(s16x8*)(Wb + i8) = *(s16x8*)o;
}

__global__ __launch_bounds__(512) void k_gi7(const int* __restrict__ inputs,
                                             const float* __restrict__ emb,
                                             const short* __restrict__ Wb,
                                             const float* __restrict__ b_ih,
                                             const uint32_t* __restrict__ M1w,
                                             float* __restrict__ GI) {
  __shared__ short As[128 * 40];
  __shared__ short Bs[304 * 40];
  __shared__ int idxs[128];
  const int t = threadIdx.x;
  const int s = blockIdx.x;
  const int lane = t & 63, wave = t >> 6;
  const int wr = wave & 1;
  const int wc = wave >> 1;
  const int ml = lane & 15, quad = lane >> 4;
  const int arow = t >> 2;
  const int akq = t & 3;

  if (t < 128) idxs[t] = inputs[t * SEQ + s];
  __syncthreads();

  const int nfr = (wc < 3) ? 5 : 4;
  f32x4 acc[4][5];
#pragma unroll
  for (int i = 0; i < 4; ++i)
#pragma unroll
    for (int j = 0; j < 5; ++j) acc[i][j] = (f32x4){0.f, 0.f, 0.f, 0.f};

  const int myidx = idxs[arow];

  for (int c = 0; c < 10; ++c) {
    const int e0 = c * 32 + akq * 8;
    float xa[8];
#pragma unroll
    for (int j = 0; j < 8; ++j) xa[j] = 0.f;
    if (e0 + 7 < 300) {
#pragma unroll
      for (int q4 = 0; q4 < 2; ++q4) {
        float4 v = *(const float4*)(emb + (size_t)myidx * EMB + e0 + q4 * 4);
        xa[q4 * 4 + 0] = v.x; xa[q4 * 4 + 1] = v.y; xa[q4 * 4 + 2] = v.z; xa[q4 * 4 + 3] = v.w;
      }
    } else if (e0 < 300) {
#pragma unroll
      for (int j = 0; j < 8; ++j) {
        int e = e0 + j;
        if (e < 300) xa[j] = emb[(size_t)myidx * EMB + e];
      }
    }
    uint32_t mb = 0;
    if (e0 < 300) {
      uint32_t base = (uint32_t)((arow * SEQ + s) * EMB + e0);
      uint64_t mw = (uint64_t)M1w[base >> 5] | ((uint64_t)M1w[(base >> 5) + 1] << 32);
      mb = (uint32_t)(mw >> (base & 31));
    }
    short sa[8];
#pragma unroll
    for (int j = 0; j < 8; ++j)
      sa[j] = f2bf(((mb >> j) & 1u) ? xa[j] * 2.f : 0.f);
    s16x8 bv0, bv1, bv2;
    {
      int i0 = t;
      bv0 = *(const s16x8*)(Wb + (size_t)(i0 >> 2) * 320 + c * 32 + (i0 & 3) * 8);
      int i1 = t + 512;
      bv1 = *(const s16x8*)(Wb + (size_t)(i1 >> 2) * 320 + c * 32 + (i1 & 3) * 8);
      if (t < 192) {
        int i2 = t + 1024;
        bv2 = *(const s16x8*)(Wb + (size_t)(i2 >> 2) * 320 + c * 32 + (i2 & 3) * 8);
      }
    }
    if (c > 0) __syncthreads();
    *(s16x8*)&As[arow * 40 + akq * 8] = *(s16x8*)&sa[0];
    {
      int i0 = t;       *(s16x8*)&Bs[(i0 >> 2) * 40 + (i0 & 3) * 8] = bv0;
      int i1 = t + 512; *(s16x8*)&Bs[(i1 >> 2) * 40 + (i1 & 3) * 8] = bv1;
      if (t < 192) { int i2 = t + 1024; *(s16x8*)&Bs[(i2 >> 2) * 40 + (i2 & 3) * 8] = bv2; }
    }
    __syncthreads();
    s16x8 af[4];
#pragma unroll
    for (int mt = 0; mt < 4; ++mt)
      af[mt] = *(const s16x8*)&As[(wr * 64 + mt * 16 + ml) * 40 + quad * 8];
#pragma unroll
    for (int j = 0; j < 5; ++j) {
      if (j < nfr) {
        int nt = wc + 4 * j;
        s16x8 bf = *(const s16x8*)&Bs[(nt * 16 + ml) * 40 + quad * 8];
#pragma unroll
        for (int mt = 0; mt < 4; ++mt)
          acc[mt][j] = __builtin_amdgcn_mfma_f32_16x16x32_bf16(af[mt], bf, acc[mt][j], 0, 0, 0);
      }
    }
  }

#pragma unroll
  for (int j = 0; j < 5; ++j) {
    if (j < nfr) {
      int n = (wc + 4 * j) * 16 + ml;
      if (n < 300) {
        float bias = b_ih[n];
#pragma unroll
        for (int mt = 0; mt < 4; ++mt) {
#pragma unroll
          for (int i = 0; i < 4; ++i) {
            int brow = wr * 64 + mt * 16 + quad * 4 + i;
            GI[(size_t)(s * BATCH + brow) * G3 + n] = acc[mt][j][i] + bias;
          }
        }
      }
    }
  }
}

__global__ __launch_bounds__(512, 1) void k_rnn11(const float* __restrict__ GI,
                                                  const float* __restrict__ w_hh,
                                                  const float* __restrict__ b_hh,
                                                  const uint8_t* __restrict__ M2,
                                                  float* __restrict__ Hd) {
  __shared__ __align__(16) uint32_t hp_s[2][64];
  const int t = threadIdx.x, b = blockIdx.x;
  const int u = t >> 2, ks = t & 3;
  const bool act = (u < 100);
  const bool gate = act && (ks == 0);
  const int uc = act ? u : 99;
  const int kplo = (ks < 2) ? ks * 13 : 26 + (ks - 2) * 12;
  const int np = (ks < 2) ? 13 : 12;

  const float* rowR = w_hh + (size_t)uc * HID;
  const float* rowZ = w_hh + (size_t)(uc + 100) * HID;
  const float* rowN = w_hh + (size_t)(uc + 200) * HID;
  const h16x2 z2 = (h16x2){(__fp16)0.f, (__fp16)0.f};
  h16x2 wR[13], wZ[13], wN[13];
#pragma unroll
  for (int j = 0; j < 13; ++j) {
    if (j < np) {
      int o = 2 * (kplo + j);
      wR[j] = __builtin_amdgcn_cvt_pkrtz(rowR[o], rowR[o + 1]);
      wZ[j] = __builtin_amdgcn_cvt_pkrtz(rowZ[o], rowZ[o + 1]);
      wN[j] = __builtin_amdgcn_cvt_pkrtz(rowN[o], rowN[o + 1]);
    } else { wR[j] = z2; wZ[j] = z2; wN[j] = z2; }
  }

  float bR0 = 0.f, bZ0 = 0.f, bN0 = 0.f;
  float gcR = 0.f, gcZ = 0.f, gcN = 0.f;
  uint8_t mc = 0;
  if (gate) {
    bR0 = b_hh[u]; bZ0 = b_hh[100 + u]; bN0 = b_hh[200 + u];
    const float* g0 = GI + (size_t)b * G3;
    gcR = g0[u]; gcZ = g0[100 + u]; gcN = g0[200 + u];
    mc = M2[(uint32_t)(b * HID + u) >> 3];
  }
  const int p = u >> 1;
  const int sidx = (p < 13) ? 0 : (p < 26) ? 1 : (p < 38) ? 2 : 3;
  const int spos = p - ((sidx < 2) ? sidx * 13 : 26 + (sidx - 2) * 12);
  const int slot = sidx * 16 + spos;
  const bool writer = gate && !(u & 1);

  if (t < 128) ((uint32_t*)hp_s)[t] = 0u;
  float hprev = 0.f;
  __syncthreads();

#define QPX(x, c) __builtin_bit_cast(float, __builtin_amdgcn_mov_dpp( \
    __builtin_bit_cast(int, (x)), (c), 0xF, 0xF, true))
#define DOT1(J, W) { h16x2 hh = __builtin_bit_cast(h16x2, (W)); \
    sR = __builtin_amdgcn_fdot2(wR[J], hh, sR, false); \
    sZ = __builtin_amdgcn_fdot2(wZ[J], hh, sZ, false); \
    sN = __builtin_amdgcn_fdot2(wN[J], hh, sN, false); }

#pragma unroll 2
  for (int s = 0; s < SEQ; ++s) {
    float gnR = 0.f, gnZ = 0.f, gnN = 0.f;
    uint8_t mn = 0;
    if (gate) {
      int sn = (s + 1 < SEQ) ? s + 1 : s;
      const float* gp = GI + (size_t)(sn * BATCH + b) * G3;
      gnR = gp[u]; gnZ = gp[100 + u]; gnN = gp[200 + u];
      mn = M2[(uint32_t)((sn * BATCH + b) * HID + u) >> 3];
    }

    if (act) {
      float sR = bR0, sZ = bZ0, sN = bN0;
      const uint32_t* hb = &hp_s[s & 1][0] + (ks << 4);
      uint4 h0 = *(const uint4*)hb;
      uint4 h1 = *(const uint4*)(hb + 4);
      uint4 h2 = *(const uint4*)(hb + 8);
      uint32_t h3 = hb[12];
      DOT1(0, h0.x)  DOT1(1, h0.y)  DOT1(2, h0.z)  DOT1(3, h0.w)
      DOT1(4, h1.x)  DOT1(5, h1.y)  DOT1(6, h1.z)  DOT1(7, h1.w)
      DOT1(8, h2.x)  DOT1(9, h2.y)  DOT1(10, h2.z) DOT1(11, h2.w)
      DOT1(12, h3)
      sR += QPX(sR, 0xB1); sZ += QPX(sZ, 0xB1); sN += QPX(sN, 0xB1);
      sR += QPX(sR, 0x4E); sZ += QPX(sZ, 0x4E); sN += QPX(sN, 0x4E);
      if (gate) {
        float r = 1.f / (1.f + __expf(-(gcR + sR)));
        float z = 1.f / (1.f + __expf(-(gcZ + sZ)));
        float xn = gcN + r * sN;
        float e2 = __expf(2.f * fabsf(xn));
        float n = copysignf(1.f - 2.f / (e2 + 1.f), xn);
        float hnew = (1.f - z) * n + z * hprev;
        hprev = hnew;
        uint32_t fl = (uint32_t)((s * BATCH + b) * HID + u);
        float hd = ((mc >> (fl & 7)) & 1) ? hnew * 2.f : 0.f;
        Hd[(size_t)(b * SEQ + s) * HID + u] = hd;
        float hoth = swz_xor4(hnew);
        if (writer)
          hp_s[(s & 1) ^ 1][slot] =
              __builtin_bit_cast(uint32_t, __builtin_amdgcn_cvt_pkrtz(hnew, hoth));
      }
    }
    gcR = gnR; gcZ = gnZ; gcN = gnN; mc = mn;
    bar_lds();
  }
#undef DOT1
#undef QPX
}

__global__ __launch_bounds__(64) void k_out(const float* __restrict__ Hd,
                                            const float* __restrict__ w_lin,
                                            const float* __restrict__ b_lin,
                                            float* __restrict__ out) {
  __shared__ float Wl[NCLS * HID];
  __shared__ float bl[NCLS];
  const int t = threadIdx.x;
  for (int i = t; i < NCLS * HID; i += 64) Wl[i] = w_lin[i];
  if (t < NCLS) bl[t] = b_lin[t];
  __syncthreads();

  const int r0 = (blockIdx.x * 64 + t) * 4;
  float acc[4][NCLS];
#pragma unroll
  for (int r = 0; r < 4; ++r)
#pragma unroll
    for (int c = 0; c < NCLS; ++c) acc[r][c] = bl[c];

  for (int k = 0; k < HID; k += 4) {
    float4 h0 = *(const float4*)(Hd + (size_t)(r0 + 0) * HID + k);
    float4 h1 = *(const float4*)(Hd + (size_t)(r0 + 1) * HID + k);
    float4 h2 = *(const float4*)(Hd + (size_t)(r0 + 2) * HID + k);
    float4 h3 = *(const float4*)(Hd + (size_t)(r0 + 3) * HID + k);
#pragma unroll
    for (int c = 0; c < NCLS; ++c) {
      float4 w4 = *(const float4*)&Wl[c * HID + k];
      acc[0][c] += h0.x * w4.x + h0.y * w4.y + h0.z * w4.z + h0.w * w4.w;
      acc[1][c] += h1.x * w4.x + h1.y * w4.y + h1.z * w4.z + h1.w * w4.w;
      acc[2][c] += h2.x * w4.x + h2.y * w4.y + h2.z * w4.z + h2.w * w4.w;
      acc[3][c] += h3.x * w4.x + h3.y * w4.y + h3.z * w4.z + h3.w * w4.w;
    }
  }

  float lse[4];
#pragma unroll
  for (int r = 0; r < 4; ++r) {
    float mx = acc[r][0];
#pragma unroll
    for (int c = 1; c < NCLS; ++c) mx = fmaxf(mx, acc[r][c]);
    float se = 0.f;
#pragma unroll
    for (int c = 0; c < NCLS; ++c) se += __expf(acc[r][c] - mx);
    lse[r] = mx + __logf(se);
  }
  const int b = r0 >> 9, s0 = r0 & 511;
#pragma unroll
  for (int c = 0; c < NCLS; ++c) {
    float4 o = make_float4(acc[0][c] - lse[0], acc[1][c] - lse[1],
                           acc[2][c] - lse[2], acc[3][c] - lse[3]);
    *(float4*)(out + (size_t)(b * NCLS + c) * SEQ + s0) = o;
  }
}

// ---------------- host ----------------
extern "C" void kernel_launch(void* const* d_in, const int* in_sizes, int n_in,
                              void* d_out, int out_size, void* d_ws, size_t ws_size,
                              hipStream_t stream) {
  const int*   inputs = (const int*)d_in[0];
  const float* emb    = (const float*)d_in[1];
  const float* w_ih   = (const float*)d_in[2];
  const float* w_hh   = (const float*)d_in[3];
  const float* b_ih   = (const float*)d_in[4];
  const float* b_hh   = (const float*)d_in[5];
  const float* w_lin  = (const float*)d_in[6];
  const float* b_lin  = (const float*)d_in[7];
  float* out = (float*)d_out;

  float* GI = (float*)d_ws;                           // 78.64 MB
  float* Hd = GI + (size_t)NROWS * G3;                // 26.21 MB
  uint8_t* M1 = (uint8_t*)(Hd + (size_t)NROWS * HID); // 2.46 MB
  uint8_t* M2 = M1 + (size_t)M1_WORDS * 4;            // 0.82 MB
  short* Wb = (short*)(M2 + (size_t)M2_WORDS * 4);    // 0.19 MB

  uint32_t dk1a, dk1b, dk2a, dk2b;
  threefry2x32(0u, 42u, 0u, 0u, &dk1a, &dk1b);
  threefry2x32(0u, 42u, 0u, 1u, &dk2a, &dk2b);

  uint32_t* M1u = (uint32_t*)M1;
  uint32_t* M2u = (uint32_t*)M2;
  void* kargs[] = {
      (void*)&inputs, (void*)&emb, (void*)&w_ih, (void*)&w_hh,
      (void*)&b_ih, (void*)&b_hh, (void*)&w_lin, (void*)&b_lin,
      (void*)&out, (void*)&GI, (void*)&Hd, (void*)&M1u, (void*)&M2u,
      (void*)&Wb, (void*)&dk1a, (void*)&dk1b, (void*)&dk2a, (void*)&dk2b };

  hipError_t err = hipLaunchCooperativeKernel((const void*)k_all, dim3(256),
                                              dim3(512), kargs, 0, stream);
  if (err != hipSuccess) {
    (void)hipGetLastError();   // clear sticky error; run legacy 5-kernel path
    k_mask<<<(M1_WORDS + M2_WORDS) / 256, 256, 0, stream>>>(
        M1u, M2u, dk1a, dk1b, dk2a, dk2b);
    k_prepw<<<(304 * 320 / 8 + 255) / 256, 256, 0, stream>>>(w_ih, Wb);
    k_gi7<<<512, 512, 0, stream>>>(inputs, emb, Wb, b_ih, M1u, GI);
    k_rnn11<<<BATCH, 512, 0, stream>>>(GI, w_hh, b_hh, M2, Hd);
    k_out<<<256, 64, 0, stream>>>(Hd, w_lin, b_lin, out);
  }
}

// Round 8
// 552.952 us; speedup vs baseline: 1.6980x; 1.6980x over previous
//
#include <hip/hip_runtime.h>
#include <hip/hip_bf16.h>
#include <cstdint>

#define BATCH 128
#define SEQ   512
#define EMB   300
#define HID   100
#define G3    300
#define NCLS  20
#define NROWS (SEQ * BATCH)

#define M1_WORDS 614400   // 128*512*300 / 32
#define M2_WORDS 204800   // 512*128*100 / 32

typedef __attribute__((ext_vector_type(4))) float f32x4;
typedef __attribute__((ext_vector_type(8))) short s16x8;
typedef __fp16 h16x2 __attribute__((ext_vector_type(2)));   // matches cvt_pkrtz return

// ---------------- threefry2x32 (JAX-compatible, verified round 1) ----------------
__host__ __device__ __forceinline__ void threefry2x32(uint32_t k0, uint32_t k1,
                                                      uint32_t x0, uint32_t x1,
                                                      uint32_t* o0, uint32_t* o1) {
  uint32_t ks2 = k0 ^ k1 ^ 0x1BD11BDAu;
  x0 += k0; x1 += k1;
#define TFR(r) { x0 += x1; x1 = (x1 << (r)) | (x1 >> (32 - (r))); x1 ^= x0; }
  TFR(13) TFR(15) TFR(26) TFR(6)  x0 += k1;  x1 += ks2 + 1u;
  TFR(17) TFR(29) TFR(16) TFR(24) x0 += ks2; x1 += k0 + 2u;
  TFR(13) TFR(15) TFR(26) TFR(6)  x0 += k0;  x1 += k1 + 3u;
  TFR(17) TFR(29) TFR(16) TFR(24) x0 += k1;  x1 += ks2 + 4u;
  TFR(13) TFR(15) TFR(26) TFR(6)  x0 += ks2; x1 += k0 + 5u;
#undef TFR
  *o0 = x0; *o1 = x1;
}

__device__ __forceinline__ uint32_t rand_bits32(uint32_t ka, uint32_t kb, uint32_t flat) {
  uint32_t a, b;
  threefry2x32(ka, kb, 0u, flat, &a, &b);
  return a ^ b;
}

__device__ __forceinline__ short f2bf(float f) {   // RNE fp32->bf16
  union { float f; uint32_t u; } c; c.f = f;
  uint32_t u = c.u;
  return (short)((u + 0x7FFFu + ((u >> 16) & 1u)) >> 16);
}

// raw barrier: LDS-only drain, no vmcnt(0)
__device__ __forceinline__ void bar_lds() {
  __asm__ __volatile__("s_waitcnt lgkmcnt(0)" ::: "memory");
  __builtin_amdgcn_s_barrier();
  __asm__ __volatile__("" ::: "memory");
}

// lane i <- lane i^4 (BitMode: xor=4, and=0x1F)
__device__ __forceinline__ float swz_xor4(float x) {
  return __builtin_bit_cast(float,
      __builtin_amdgcn_ds_swizzle(__builtin_bit_cast(int, x), 0x101F));
}

// ---------------- D1: masks (M1+M2) + Wb prep, concatenated by blockIdx --------
// blocks [0,3200): mask body verbatim (3200*256 = M1_WORDS+M2_WORDS exactly).
// blocks [3200,3248): prepw body (304*320/8 = 12160 chunks).
__global__ __launch_bounds__(256) void k_prep(uint32_t* __restrict__ M1w,
                                              uint32_t* __restrict__ M2w,
                                              const float* __restrict__ w_ih,
                                              short* __restrict__ Wb,
                                              uint32_t k1a, uint32_t k1b,
                                              uint32_t k2a, uint32_t k2b) {
  const int bid = blockIdx.x;
  if (bid < 3200) {
    const int i = bid * 256 + threadIdx.x;
    uint32_t ka, kb, base;
    uint32_t* dst;
    if (i < M1_WORDS) { ka = k1a; kb = k1b; base = (uint32_t)i * 32u; dst = M1w + i; }
    else { ka = k2a; kb = k2b; base = (uint32_t)(i - M1_WORDS) * 32u; dst = M2w + (i - M1_WORDS); }
    uint32_t w = 0u;
#pragma unroll
    for (int j = 0; j < 32; ++j) {
      uint32_t bits = rand_bits32(ka, kb, base + (uint32_t)j);
      w |= ((~bits) >> 31) << j;
    }
    *dst = w;
  } else {
    int i8 = ((bid - 3200) * 256 + threadIdx.x) * 8;
    if (i8 >= 304 * 320) return;
    short o[8];
#pragma unroll
    for (int j = 0; j < 8; ++j) {
      int pos = i8 + j;
      int n = pos / 320, k = pos - (pos / 320) * 320;
      float v = (n < 300 && k < 300) ? w_ih[(size_t)n * EMB + k] : 0.f;
      o[j] = f2bf(v);
    }
    *(s16x8*)(Wb + i8) = *(s16x8*)o;
  }
}

// ---------------- D2: per-batch GEMM -> RNN -> logits, ONE block per batch ------
// 128 blocks x 512 threads, three phases with block-local barriers only.
// Phase 1: gi7 body re-indexed (block=b, rows=s; 4 M-tiles of 128 s-rows),
//          writing block-private contiguous GIb[512][300].
// Phase 2: rnn11 body verbatim; gi loads from GIb (L2-hot, same CU wrote it).
// Phase 3: k_out body, 1 row/thread (s = t).
__global__ __launch_bounds__(512, 1) void k_main(const int* __restrict__ inputs,
                                                 const float* __restrict__ emb,
                                                 const short* __restrict__ Wb,
                                                 const float* __restrict__ b_ih,
                                                 const uint32_t* __restrict__ M1w,
                                                 float* __restrict__ GI,
                                                 const float* __restrict__ w_hh,
                                                 const float* __restrict__ b_hh,
                                                 const uint8_t* __restrict__ M2,
                                                 float* __restrict__ Hd,
                                                 const float* __restrict__ w_lin,
                                                 const float* __restrict__ b_lin,
                                                 float* __restrict__ out) {
  __shared__ __align__(16) char smem[35072];   // As(10240)+Bs(24320)+idxs(512)
  const int t = threadIdx.x, b = blockIdx.x;
  float* GIb = GI + (size_t)b * SEQ * G3;      // block-private [512][300]

  // ===================== Phase 1: GI GEMM (gi7 body, s-rows) =====================
  {
    short* As = (short*)smem;                  // [128*40]
    short* Bs = As + 128 * 40;                 // [304*40]
    int* idxs = (int*)(Bs + 304 * 40);         // [128]
    const int lane = t & 63, wave = t >> 6;
    const int wr = wave & 1, wc = wave >> 1;
    const int ml = lane & 15, quad = lane >> 4;
    const int arow = t >> 2, akq = t & 3;
    const int nfr = (wc < 3) ? 5 : 4;

    for (int tile = 0; tile < 4; ++tile) {
      __syncthreads();                         // guard As/Bs/idxs vs prev tile reads
      if (t < 128) idxs[t] = inputs[b * SEQ + tile * 128 + t];
      __syncthreads();

      f32x4 acc[4][5];
#pragma unroll
      for (int i = 0; i < 4; ++i)
#pragma unroll
        for (int j = 0; j < 5; ++j) acc[i][j] = (f32x4){0.f, 0.f, 0.f, 0.f};

      const int myidx = idxs[arow];
      const int srow = tile * 128 + arow;

      for (int c = 0; c < 10; ++c) {
        const int e0 = c * 32 + akq * 8;
        float xa[8];
#pragma unroll
        for (int j = 0; j < 8; ++j) xa[j] = 0.f;
        if (e0 + 7 < 300) {
#pragma unroll
          for (int q4 = 0; q4 < 2; ++q4) {
            float4 v = *(const float4*)(emb + (size_t)myidx * EMB + e0 + q4 * 4);
            xa[q4 * 4 + 0] = v.x; xa[q4 * 4 + 1] = v.y;
            xa[q4 * 4 + 2] = v.z; xa[q4 * 4 + 3] = v.w;
          }
        } else if (e0 < 300) {
#pragma unroll
          for (int j = 0; j < 8; ++j) {
            int e = e0 + j;
            if (e < 300) xa[j] = emb[(size_t)myidx * EMB + e];
          }
        }
        uint32_t mb = 0;
        if (e0 < 300) {
          uint32_t base = (uint32_t)((b * SEQ + srow) * EMB + e0);
          uint64_t mw = (uint64_t)M1w[base >> 5] | ((uint64_t)M1w[(base >> 5) + 1] << 32);
          mb = (uint32_t)(mw >> (base & 31));
        }
        short sa[8];
#pragma unroll
        for (int j = 0; j < 8; ++j)
          sa[j] = f2bf(((mb >> j) & 1u) ? xa[j] * 2.f : 0.f);
        s16x8 bv0, bv1, bv2;
        {
          int i0 = t;
          bv0 = *(const s16x8*)(Wb + (size_t)(i0 >> 2) * 320 + c * 32 + (i0 & 3) * 8);
          int i1 = t + 512;
          bv1 = *(const s16x8*)(Wb + (size_t)(i1 >> 2) * 320 + c * 32 + (i1 & 3) * 8);
          if (t < 192) {
            int i2 = t + 1024;
            bv2 = *(const s16x8*)(Wb + (size_t)(i2 >> 2) * 320 + c * 32 + (i2 & 3) * 8);
          }
        }
        if (c > 0) __syncthreads();
        *(s16x8*)&As[arow * 40 + akq * 8] = *(s16x8*)&sa[0];
        {
          int i0 = t;       *(s16x8*)&Bs[(i0 >> 2) * 40 + (i0 & 3) * 8] = bv0;
          int i1 = t + 512; *(s16x8*)&Bs[(i1 >> 2) * 40 + (i1 & 3) * 8] = bv1;
          if (t < 192) { int i2 = t + 1024; *(s16x8*)&Bs[(i2 >> 2) * 40 + (i2 & 3) * 8] = bv2; }
        }
        __syncthreads();
        s16x8 af[4];
#pragma unroll
        for (int mt = 0; mt < 4; ++mt)
          af[mt] = *(const s16x8*)&As[(wr * 64 + mt * 16 + ml) * 40 + quad * 8];
#pragma unroll
        for (int j = 0; j < 5; ++j) {
          if (j < nfr) {
            int nt = wc + 4 * j;
            s16x8 bf = *(const s16x8*)&Bs[(nt * 16 + ml) * 40 + quad * 8];
#pragma unroll
            for (int mt = 0; mt < 4; ++mt)
              acc[mt][j] = __builtin_amdgcn_mfma_f32_16x16x32_bf16(af[mt], bf, acc[mt][j], 0, 0, 0);
          }
        }
      }

#pragma unroll
      for (int j = 0; j < 5; ++j) {
        if (j < nfr) {
          int n = (wc + 4 * j) * 16 + ml;
          if (n < 300) {
            float bias = b_ih[n];
#pragma unroll
            for (int mt = 0; mt < 4; ++mt) {
#pragma unroll
              for (int i = 0; i < 4; ++i) {
                int so = tile * 128 + wr * 64 + mt * 16 + quad * 4 + i;
                GIb[(size_t)so * G3 + n] = acc[mt][j][i] + bias;
              }
            }
          }
        }
      }
    }
  }
  __threadfence_block();
  __syncthreads();   // full drain: GIb stores visible to this block's loads

  // ===================== Phase 2: RNN (rnn11 body, GIb-local) =====================
  {
    uint32_t (*hp_s)[64] = (uint32_t (*)[64])smem;   // [2][64]
    const int u = t >> 2, ks = t & 3;
    const bool act = (u < 100);
    const bool gate = act && (ks == 0);
    const int uc = act ? u : 99;
    const int kplo = (ks < 2) ? ks * 13 : 26 + (ks - 2) * 12;
    const int np = (ks < 2) ? 13 : 12;

    const float* rowR = w_hh + (size_t)uc * HID;
    const float* rowZ = w_hh + (size_t)(uc + 100) * HID;
    const float* rowN = w_hh + (size_t)(uc + 200) * HID;
    const h16x2 z2 = (h16x2){(__fp16)0.f, (__fp16)0.f};
    h16x2 wR[13], wZ[13], wN[13];
#pragma unroll
    for (int j = 0; j < 13; ++j) {
      if (j < np) {
        int o = 2 * (kplo + j);
        wR[j] = __builtin_amdgcn_cvt_pkrtz(rowR[o], rowR[o + 1]);
        wZ[j] = __builtin_amdgcn_cvt_pkrtz(rowZ[o], rowZ[o + 1]);
        wN[j] = __builtin_amdgcn_cvt_pkrtz(rowN[o], rowN[o + 1]);
      } else { wR[j] = z2; wZ[j] = z2; wN[j] = z2; }
    }

    float bR0 = 0.f, bZ0 = 0.f, bN0 = 0.f;
    float gcR = 0.f, gcZ = 0.f, gcN = 0.f;
    uint8_t mc = 0;
    if (gate) {
      bR0 = b_hh[u]; bZ0 = b_hh[100 + u]; bN0 = b_hh[200 + u];
      gcR = GIb[u]; gcZ = GIb[100 + u]; gcN = GIb[200 + u];
      mc = M2[(uint32_t)(b * HID + u) >> 3];
    }
    const int p = u >> 1;
    const int sidx = (p < 13) ? 0 : (p < 26) ? 1 : (p < 38) ? 2 : 3;
    const int spos = p - ((sidx < 2) ? sidx * 13 : 26 + (sidx - 2) * 12);
    const int slot = sidx * 16 + spos;
    const bool writer = gate && !(u & 1);

    if (t < 128) ((uint32_t*)hp_s)[t] = 0u;
    float hprev = 0.f;
    __syncthreads();

#define QPX(x, c) __builtin_bit_cast(float, __builtin_amdgcn_mov_dpp( \
    __builtin_bit_cast(int, (x)), (c), 0xF, 0xF, true))
#define DOT1(J, W) { h16x2 hh = __builtin_bit_cast(h16x2, (W)); \
    sR = __builtin_amdgcn_fdot2(wR[J], hh, sR, false); \
    sZ = __builtin_amdgcn_fdot2(wZ[J], hh, sZ, false); \
    sN = __builtin_amdgcn_fdot2(wN[J], hh, sN, false); }

#pragma unroll 2
    for (int s = 0; s < SEQ; ++s) {
      float gnR = 0.f, gnZ = 0.f, gnN = 0.f;
      uint8_t mn = 0;
      if (gate) {
        int sn = (s + 1 < SEQ) ? s + 1 : s;
        const float* gp = GIb + (size_t)sn * G3;
        gnR = gp[u]; gnZ = gp[100 + u]; gnN = gp[200 + u];
        mn = M2[(uint32_t)((sn * BATCH + b) * HID + u) >> 3];
      }

      if (act) {
        float sR = bR0, sZ = bZ0, sN = bN0;
        const uint32_t* hb = &hp_s[s & 1][0] + (ks << 4);
        uint4 h0 = *(const uint4*)hb;
        uint4 h1 = *(const uint4*)(hb + 4);
        uint4 h2 = *(const uint4*)(hb + 8);
        uint32_t h3 = hb[12];
        DOT1(0, h0.x)  DOT1(1, h0.y)  DOT1(2, h0.z)  DOT1(3, h0.w)
        DOT1(4, h1.x)  DOT1(5, h1.y)  DOT1(6, h1.z)  DOT1(7, h1.w)
        DOT1(8, h2.x)  DOT1(9, h2.y)  DOT1(10, h2.z) DOT1(11, h2.w)
        DOT1(12, h3)
        sR += QPX(sR, 0xB1); sZ += QPX(sZ, 0xB1); sN += QPX(sN, 0xB1);
        sR += QPX(sR, 0x4E); sZ += QPX(sZ, 0x4E); sN += QPX(sN, 0x4E);
        if (gate) {
          float r = 1.f / (1.f + __expf(-(gcR + sR)));
          float z = 1.f / (1.f + __expf(-(gcZ + sZ)));
          float xn = gcN + r * sN;
          float e2 = __expf(2.f * fabsf(xn));
          float n = copysignf(1.f - 2.f / (e2 + 1.f), xn);
          float hnew = (1.f - z) * n + z * hprev;
          hprev = hnew;
          uint32_t fl = (uint32_t)((s * BATCH + b) * HID + u);
          float hd = ((mc >> (fl & 7)) & 1) ? hnew * 2.f : 0.f;
          Hd[(size_t)(b * SEQ + s) * HID + u] = hd;
          float hoth = swz_xor4(hnew);
          if (writer)
            hp_s[(s & 1) ^ 1][slot] =
                __builtin_bit_cast(uint32_t, __builtin_amdgcn_cvt_pkrtz(hnew, hoth));
        }
      }
      gcR = gnR; gcZ = gnZ; gcN = gnN; mc = mn;
      bar_lds();
    }
#undef DOT1
#undef QPX
  }

  // ===================== Phase 3: logits + log_softmax =====================
  {
    float* Wl = (float*)smem;          // 2000 floats
    float* bl = Wl + NCLS * HID;       // 20 floats
    __syncthreads();   // full drain: Hd stores visible; hp_s reads done
    for (int i = t; i < NCLS * HID; i += 512) Wl[i] = w_lin[i];
    if (t < NCLS) bl[t] = b_lin[t];
    __syncthreads();

    const int s = t;   // 512 threads <-> 512 rows of this batch
    const float* hrow = Hd + ((size_t)b * SEQ + s) * HID;
    float acc[NCLS];
#pragma unroll
    for (int c = 0; c < NCLS; ++c) acc[c] = bl[c];
    for (int k = 0; k < HID; k += 4) {
      const float4 h = *(const float4*)(hrow + k);
#pragma unroll
      for (int c = 0; c < NCLS; ++c) {
        const float4 w4 = *(const float4*)&Wl[c * HID + k];
        acc[c] += h.x * w4.x + h.y * w4.y + h.z * w4.z + h.w * w4.w;
      }
    }
    float mx = acc[0];
#pragma unroll
    for (int c = 1; c < NCLS; ++c) mx = fmaxf(mx, acc[c]);
    float se = 0.f;
#pragma unroll
    for (int c = 0; c < NCLS; ++c) se += __expf(acc[c] - mx);
    const float lse = mx + __logf(se);
#pragma unroll
    for (int c = 0; c < NCLS; ++c)
      out[(size_t)(b * NCLS + c) * SEQ + s] = acc[c] - lse;
  }
}

// ---------------- host ----------------
extern "C" void kernel_launch(void* const* d_in, const int* in_sizes, int n_in,
                              void* d_out, int out_size, void* d_ws, size_t ws_size,
                              hipStream_t stream) {
  const int*   inputs = (const int*)d_in[0];
  const float* emb    = (const float*)d_in[1];
  const float* w_ih   = (const float*)d_in[2];
  const float* w_hh   = (const float*)d_in[3];
  const float* b_ih   = (const float*)d_in[4];
  const float* b_hh   = (const float*)d_in[5];
  const float* w_lin  = (const float*)d_in[6];
  const float* b_lin  = (const float*)d_in[7];
  float* out = (float*)d_out;

  float* GI = (float*)d_ws;                           // 78.64 MB, [b][s][300]
  float* Hd = GI + (size_t)NROWS * G3;                // 26.21 MB
  uint8_t* M1 = (uint8_t*)(Hd + (size_t)NROWS * HID); // 2.46 MB
  uint8_t* M2 = M1 + (size_t)M1_WORDS * 4;            // 0.82 MB
  short* Wb = (short*)(M2 + (size_t)M2_WORDS * 4);    // 0.19 MB

  uint32_t dk1a, dk1b, dk2a, dk2b;
  threefry2x32(0u, 42u, 0u, 0u, &dk1a, &dk1b);
  threefry2x32(0u, 42u, 0u, 1u, &dk2a, &dk2b);

  k_prep<<<3248, 256, 0, stream>>>((uint32_t*)M1, (uint32_t*)M2, w_ih, Wb,
                                   dk1a, dk1b, dk2a, dk2b);
  k_main<<<BATCH, 512, 0, stream>>>(inputs, emb, Wb, b_ih, (const uint32_t*)M1,
                                    GI, w_hh, b_hh, M2, Hd, w_lin, b_lin, out);
}

// Round 9
// 538.507 us; speedup vs baseline: 1.7435x; 1.0268x over previous
//
#include <hip/hip_runtime.h>
#include <hip/hip_bf16.h>
#include <cstdint>

#define BATCH 128
#define SEQ   512
#define EMB   300
#define HID   100
#define G3    300
#define NCLS  20
#define NROWS (SEQ * BATCH)

#define M1_WORDS 614400   // 128*512*300 / 32
#define M2_WORDS 204800   // 512*128*100 / 32

typedef __attribute__((ext_vector_type(4))) float f32x4;
typedef __attribute__((ext_vector_type(8))) short s16x8;
typedef __fp16 h16x2 __attribute__((ext_vector_type(2)));   // matches cvt_pkrtz return

// ---------------- threefry2x32 (JAX-compatible, verified round 1) ----------------
__host__ __device__ __forceinline__ void threefry2x32(uint32_t k0, uint32_t k1,
                                                      uint32_t x0, uint32_t x1,
                                                      uint32_t* o0, uint32_t* o1) {
  uint32_t ks2 = k0 ^ k1 ^ 0x1BD11BDAu;
  x0 += k0; x1 += k1;
#define TFR(r) { x0 += x1; x1 = (x1 << (r)) | (x1 >> (32 - (r))); x1 ^= x0; }
  TFR(13) TFR(15) TFR(26) TFR(6)  x0 += k1;  x1 += ks2 + 1u;
  TFR(17) TFR(29) TFR(16) TFR(24) x0 += ks2; x1 += k0 + 2u;
  TFR(13) TFR(15) TFR(26) TFR(6)  x0 += k0;  x1 += k1 + 3u;
  TFR(17) TFR(29) TFR(16) TFR(24) x0 += k1;  x1 += ks2 + 4u;
  TFR(13) TFR(15) TFR(26) TFR(6)  x0 += ks2; x1 += k0 + 5u;
#undef TFR
  *o0 = x0; *o1 = x1;
}

__device__ __forceinline__ uint32_t rand_bits32(uint32_t ka, uint32_t kb, uint32_t flat) {
  uint32_t a, b;
  threefry2x32(ka, kb, 0u, flat, &a, &b);
  return a ^ b;
}

__device__ __forceinline__ short f2bf(float f) {   // RNE fp32->bf16
  union { float f; uint32_t u; } c; c.f = f;
  uint32_t u = c.u;
  return (short)((u + 0x7FFFu + ((u >> 16) & 1u)) >> 16);
}

// raw barrier: LDS-only drain, no vmcnt(0)
__device__ __forceinline__ void bar_lds() {
  __asm__ __volatile__("s_waitcnt lgkmcnt(0)" ::: "memory");
  __builtin_amdgcn_s_barrier();
  __asm__ __volatile__("" ::: "memory");
}

// lane i <- lane i^4 (BitMode: xor=4, and=0x1F)
__device__ __forceinline__ float swz_xor4(float x) {
  return __builtin_bit_cast(float,
      __builtin_amdgcn_ds_swizzle(__builtin_bit_cast(int, x), 0x101F));
}

// ---------------- D1: masks (M1+M2) + Wb prep, concatenated by blockIdx --------
__global__ __launch_bounds__(256) void k_prep(uint32_t* __restrict__ M1w,
                                              uint32_t* __restrict__ M2w,
                                              const float* __restrict__ w_ih,
                                              short* __restrict__ Wb,
                                              uint32_t k1a, uint32_t k1b,
                                              uint32_t k2a, uint32_t k2b) {
  const int bid = blockIdx.x;
  if (bid < 3200) {
    const int i = bid * 256 + threadIdx.x;
    uint32_t ka, kb, base;
    uint32_t* dst;
    if (i < M1_WORDS) { ka = k1a; kb = k1b; base = (uint32_t)i * 32u; dst = M1w + i; }
    else { ka = k2a; kb = k2b; base = (uint32_t)(i - M1_WORDS) * 32u; dst = M2w + (i - M1_WORDS); }
    uint32_t w = 0u;
#pragma unroll
    for (int j = 0; j < 32; ++j) {
      uint32_t bits = rand_bits32(ka, kb, base + (uint32_t)j);
      w |= ((~bits) >> 31) << j;
    }
    *dst = w;
  } else {
    int i8 = ((bid - 3200) * 256 + threadIdx.x) * 8;
    if (i8 >= 304 * 320) return;
    short o[8];
#pragma unroll
    for (int j = 0; j < 8; ++j) {
      int pos = i8 + j;
      int n = pos / 320, k = pos - (pos / 320) * 320;
      float v = (n < 300 && k < 300) ? w_ih[(size_t)n * EMB + k] : 0.f;
      o[j] = f2bf(v);
    }
    *(s16x8*)(Wb + i8) = *(s16x8*)o;
  }
}

// ---------------- D2: per-batch GEMM -> RNN -> logits, ONE block per batch ------
// Phase 1 v2: SOFTWARE-PIPELINED c-loop. Global loads (emb gather + M1 words +
// Wb rows) for iteration c+1 are issued right after the publish barrier of c,
// a full MFMA-phase + 2 barriers before consumption -> gather latency hidden.
// idxs loaded once for all 4 tiles. Phases 2/3 verbatim from R8.
__global__ __launch_bounds__(512, 1) void k_main(const int* __restrict__ inputs,
                                                 const float* __restrict__ emb,
                                                 const short* __restrict__ Wb,
                                                 const float* __restrict__ b_ih,
                                                 const uint32_t* __restrict__ M1w,
                                                 float* __restrict__ GI,
                                                 const float* __restrict__ w_hh,
                                                 const float* __restrict__ b_hh,
                                                 const uint8_t* __restrict__ M2,
                                                 float* __restrict__ Hd,
                                                 const float* __restrict__ w_lin,
                                                 const float* __restrict__ b_lin,
                                                 float* __restrict__ out) {
  __shared__ __align__(16) char smem[36608];   // As(10240)+Bs(24320)+idxs(2048)
  const int t = threadIdx.x, b = blockIdx.x;
  float* GIb = GI + (size_t)b * SEQ * G3;      // block-private [512][300]

  // ===================== Phase 1: pipelined GI GEMM =====================
  {
    short* As = (short*)smem;                  // [128*40]
    short* Bs = As + 128 * 40;                 // [304*40]
    int* idxs = (int*)(Bs + 304 * 40);         // [512] - all tiles
    const int lane = t & 63, wave = t >> 6;
    const int wr = wave & 1, wc = wave >> 1;
    const int ml = lane & 15, quad = lane >> 4;
    const int arow = t >> 2, akq = t & 3;
    const int nfr = (wc < 3) ? 5 : 4;

    idxs[t] = inputs[b * SEQ + t];
    __syncthreads();

    // pipeline registers (hold data for the CURRENT (tile,c) at consume time)
    float4 pv0, pv1;
    uint32_t pm0, pm1;
    s16x8 pb0, pb1, pb2;

#define LOADAB(TILE, C) { \
      const int e0_ = (C) * 32 + akq * 8; \
      const int myidx_ = idxs[(TILE) * 128 + arow]; \
      pv0 = make_float4(0.f, 0.f, 0.f, 0.f); pv1 = make_float4(0.f, 0.f, 0.f, 0.f); \
      pm0 = 0u; pm1 = 0u; \
      const float* er_ = emb + (size_t)myidx_ * EMB; \
      if (e0_ + 7 < 300) { pv0 = *(const float4*)(er_ + e0_); pv1 = *(const float4*)(er_ + e0_ + 4); } \
      else if (e0_ < 300) { pv0 = *(const float4*)(er_ + e0_); } \
      if (e0_ < 300) { \
        uint32_t base_ = (uint32_t)((b * SEQ + (TILE) * 128 + arow) * EMB + e0_); \
        pm0 = M1w[base_ >> 5]; pm1 = M1w[(base_ >> 5) + 1]; \
      } \
      { int i0_ = t;        pb0 = *(const s16x8*)(Wb + (size_t)(i0_ >> 2) * 320 + (C) * 32 + (i0_ & 3) * 8); \
        int i1_ = t + 512;  pb1 = *(const s16x8*)(Wb + (size_t)(i1_ >> 2) * 320 + (C) * 32 + (i1_ & 3) * 8); \
        if (t < 192) { int i2_ = t + 1024; \
          pb2 = *(const s16x8*)(Wb + (size_t)(i2_ >> 2) * 320 + (C) * 32 + (i2_ & 3) * 8); } } \
    }

    LOADAB(0, 0)   // prologue

    for (int tile = 0; tile < 4; ++tile) {
      f32x4 acc[4][5];
#pragma unroll
      for (int i = 0; i < 4; ++i)
#pragma unroll
        for (int j = 0; j < 5; ++j) acc[i][j] = (f32x4){0.f, 0.f, 0.f, 0.f};

      for (int c = 0; c < 10; ++c) {
        if (!(tile == 0 && c == 0)) __syncthreads();   // prior LDS consumers done
        // ---- convert + store from pipeline regs (data for this tile,c) ----
        {
          const int e0 = c * 32 + akq * 8;
          uint32_t mb = 0;
          if (e0 < 300) {
            uint32_t base = (uint32_t)((b * SEQ + tile * 128 + arow) * EMB + e0);
            uint64_t mw = (uint64_t)pm0 | ((uint64_t)pm1 << 32);
            mb = (uint32_t)(mw >> (base & 31));
          }
          float xa[8];
          xa[0] = pv0.x; xa[1] = pv0.y; xa[2] = pv0.z; xa[3] = pv0.w;
          xa[4] = pv1.x; xa[5] = pv1.y; xa[6] = pv1.z; xa[7] = pv1.w;
          short sa[8];
#pragma unroll
          for (int j = 0; j < 8; ++j)
            sa[j] = f2bf(((mb >> j) & 1u) ? xa[j] * 2.f : 0.f);
          *(s16x8*)&As[arow * 40 + akq * 8] = *(s16x8*)&sa[0];
          int i0 = t;       *(s16x8*)&Bs[(i0 >> 2) * 40 + (i0 & 3) * 8] = pb0;
          int i1 = t + 512; *(s16x8*)&Bs[(i1 >> 2) * 40 + (i1 & 3) * 8] = pb1;
          if (t < 192) { int i2 = t + 1024; *(s16x8*)&Bs[(i2 >> 2) * 40 + (i2 & 3) * 8] = pb2; }
        }
        __syncthreads();                               // publish c

        // ---- prefetch next iteration's globals (hidden under MFMA below) ----
        {
          int nc = c + 1, ntile = tile;
          if (nc == 10) { nc = 0; ++ntile; }
          if (ntile < 4) LOADAB(ntile, nc)
        }

        // ---- MFMA on current c ----
        s16x8 af[4];
#pragma unroll
        for (int mt = 0; mt < 4; ++mt)
          af[mt] = *(const s16x8*)&As[(wr * 64 + mt * 16 + ml) * 40 + quad * 8];
#pragma unroll
        for (int j = 0; j < 5; ++j) {
          if (j < nfr) {
            int nt = wc + 4 * j;
            s16x8 bf = *(const s16x8*)&Bs[(nt * 16 + ml) * 40 + quad * 8];
#pragma unroll
            for (int mt = 0; mt < 4; ++mt)
              acc[mt][j] = __builtin_amdgcn_mfma_f32_16x16x32_bf16(af[mt], bf, acc[mt][j], 0, 0, 0);
          }
        }
      }

#pragma unroll
      for (int j = 0; j < 5; ++j) {
        if (j < nfr) {
          int n = (wc + 4 * j) * 16 + ml;
          if (n < 300) {
            float bias = b_ih[n];
#pragma unroll
            for (int mt = 0; mt < 4; ++mt) {
#pragma unroll
              for (int i = 0; i < 4; ++i) {
                int so = tile * 128 + wr * 64 + mt * 16 + quad * 4 + i;
                GIb[(size_t)so * G3 + n] = acc[mt][j][i] + bias;
              }
            }
          }
        }
      }
    }
#undef LOADAB
  }
  __threadfence_block();
  __syncthreads();   // full drain: GIb stores visible to this block's loads

  // ===================== Phase 2: RNN (rnn11 body, GIb-local) =====================
  {
    uint32_t (*hp_s)[64] = (uint32_t (*)[64])smem;   // [2][64]
    const int u = t >> 2, ks = t & 3;
    const bool act = (u < 100);
    const bool gate = act && (ks == 0);
    const int uc = act ? u : 99;
    const int kplo = (ks < 2) ? ks * 13 : 26 + (ks - 2) * 12;
    const int np = (ks < 2) ? 13 : 12;

    const float* rowR = w_hh + (size_t)uc * HID;
    const float* rowZ = w_hh + (size_t)(uc + 100) * HID;
    const float* rowN = w_hh + (size_t)(uc + 200) * HID;
    const h16x2 z2 = (h16x2){(__fp16)0.f, (__fp16)0.f};
    h16x2 wR[13], wZ[13], wN[13];
#pragma unroll
    for (int j = 0; j < 13; ++j) {
      if (j < np) {
        int o = 2 * (kplo + j);
        wR[j] = __builtin_amdgcn_cvt_pkrtz(rowR[o], rowR[o + 1]);
        wZ[j] = __builtin_amdgcn_cvt_pkrtz(rowZ[o], rowZ[o + 1]);
        wN[j] = __builtin_amdgcn_cvt_pkrtz(rowN[o], rowN[o + 1]);
      } else { wR[j] = z2; wZ[j] = z2; wN[j] = z2; }
    }

    float bR0 = 0.f, bZ0 = 0.f, bN0 = 0.f;
    float gcR = 0.f, gcZ = 0.f, gcN = 0.f;
    uint8_t mc = 0;
    if (gate) {
      bR0 = b_hh[u]; bZ0 = b_hh[100 + u]; bN0 = b_hh[200 + u];
      gcR = GIb[u]; gcZ = GIb[100 + u]; gcN = GIb[200 + u];
      mc = M2[(uint32_t)(b * HID + u) >> 3];
    }
    const int p = u >> 1;
    const int sidx = (p < 13) ? 0 : (p < 26) ? 1 : (p < 38) ? 2 : 3;
    const int spos = p - ((sidx < 2) ? sidx * 13 : 26 + (sidx - 2) * 12);
    const int slot = sidx * 16 + spos;
    const bool writer = gate && !(u & 1);

    if (t < 128) ((uint32_t*)hp_s)[t] = 0u;
    float hprev = 0.f;
    __syncthreads();

#define QPX(x, c) __builtin_bit_cast(float, __builtin_amdgcn_mov_dpp( \
    __builtin_bit_cast(int, (x)), (c), 0xF, 0xF, true))
#define DOT1(J, W) { h16x2 hh = __builtin_bit_cast(h16x2, (W)); \
    sR = __builtin_amdgcn_fdot2(wR[J], hh, sR, false); \
    sZ = __builtin_amdgcn_fdot2(wZ[J], hh, sZ, false); \
    sN = __builtin_amdgcn_fdot2(wN[J], hh, sN, false); }

#pragma unroll 2
    for (int s = 0; s < SEQ; ++s) {
      float gnR = 0.f, gnZ = 0.f, gnN = 0.f;
      uint8_t mn = 0;
      if (gate) {
        int sn = (s + 1 < SEQ) ? s + 1 : s;
        const float* gp = GIb + (size_t)sn * G3;
        gnR = gp[u]; gnZ = gp[100 + u]; gnN = gp[200 + u];
        mn = M2[(uint32_t)((sn * BATCH + b) * HID + u) >> 3];
      }

      if (act) {
        float sR = bR0, sZ = bZ0, sN = bN0;
        const uint32_t* hb = &hp_s[s & 1][0] + (ks << 4);
        uint4 h0 = *(const uint4*)hb;
        uint4 h1 = *(const uint4*)(hb + 4);
        uint4 h2 = *(const uint4*)(hb + 8);
        uint32_t h3 = hb[12];
        DOT1(0, h0.x)  DOT1(1, h0.y)  DOT1(2, h0.z)  DOT1(3, h0.w)
        DOT1(4, h1.x)  DOT1(5, h1.y)  DOT1(6, h1.z)  DOT1(7, h1.w)
        DOT1(8, h2.x)  DOT1(9, h2.y)  DOT1(10, h2.z) DOT1(11, h2.w)
        DOT1(12, h3)
        sR += QPX(sR, 0xB1); sZ += QPX(sZ, 0xB1); sN += QPX(sN, 0xB1);
        sR += QPX(sR, 0x4E); sZ += QPX(sZ, 0x4E); sN += QPX(sN, 0x4E);
        if (gate) {
          float r = 1.f / (1.f + __expf(-(gcR + sR)));
          float z = 1.f / (1.f + __expf(-(gcZ + sZ)));
          float xn = gcN + r * sN;
          float e2 = __expf(2.f * fabsf(xn));
          float n = copysignf(1.f - 2.f / (e2 + 1.f), xn);
          float hnew = (1.f - z) * n + z * hprev;
          hprev = hnew;
          uint32_t fl = (uint32_t)((s * BATCH + b) * HID + u);
          float hd = ((mc >> (fl & 7)) & 1) ? hnew * 2.f : 0.f;
          Hd[(size_t)(b * SEQ + s) * HID + u] = hd;
          float hoth = swz_xor4(hnew);
          if (writer)
            hp_s[(s & 1) ^ 1][slot] =
                __builtin_bit_cast(uint32_t, __builtin_amdgcn_cvt_pkrtz(hnew, hoth));
        }
      }
      gcR = gnR; gcZ = gnZ; gcN = gnN; mc = mn;
      bar_lds();
    }
#undef DOT1
#undef QPX
  }

  // ===================== Phase 3: logits + log_softmax =====================
  {
    float* Wl = (float*)smem;          // 2000 floats
    float* bl = Wl + NCLS * HID;       // 20 floats
    __syncthreads();   // full drain: Hd stores visible; hp_s reads done
    for (int i = t; i < NCLS * HID; i += 512) Wl[i] = w_lin[i];
    if (t < NCLS) bl[t] = b_lin[t];
    __syncthreads();

    const int s = t;   // 512 threads <-> 512 rows of this batch
    const float* hrow = Hd + ((size_t)b * SEQ + s) * HID;
    float acc[NCLS];
#pragma unroll
    for (int c = 0; c < NCLS; ++c) acc[c] = bl[c];
    for (int k = 0; k < HID; k += 4) {
      const float4 h = *(const float4*)(hrow + k);
#pragma unroll
      for (int c = 0; c < NCLS; ++c) {
        const float4 w4 = *(const float4*)&Wl[c * HID + k];
        acc[c] += h.x * w4.x + h.y * w4.y + h.z * w4.z + h.w * w4.w;
      }
    }
    float mx = acc[0];
#pragma unroll
    for (int c = 1; c < NCLS; ++c) mx = fmaxf(mx, acc[c]);
    float se = 0.f;
#pragma unroll
    for (int c = 0; c < NCLS; ++c) se += __expf(acc[c] - mx);
    const float lse = mx + __logf(se);
#pragma unroll
    for (int c = 0; c < NCLS; ++c)
      out[(size_t)(b * NCLS + c) * SEQ + s] = acc[c] - lse;
  }
}

// ---------------- host ----------------
extern "C" void kernel_launch(void* const* d_in, const int* in_sizes, int n_in,
                              void* d_out, int out_size, void* d_ws, size_t ws_size,
                              hipStream_t stream) {
  const int*   inputs = (const int*)d_in[0];
  const float* emb    = (const float*)d_in[1];
  const float* w_ih   = (const float*)d_in[2];
  const float* w_hh   = (const float*)d_in[3];
  const float* b_ih   = (const float*)d_in[4];
  const float* b_hh   = (const float*)d_in[5];
  const float* w_lin  = (const float*)d_in[6];
  const float* b_lin  = (const float*)d_in[7];
  float* out = (float*)d_out;

  float* GI = (float*)d_ws;                           // 78.64 MB, [b][s][300]
  float* Hd = GI + (size_t)NROWS * G3;                // 26.21 MB
  uint8_t* M1 = (uint8_t*)(Hd + (size_t)NROWS * HID); // 2.46 MB
  uint8_t* M2 = M1 + (size_t)M1_WORDS * 4;            // 0.82 MB
  short* Wb = (short*)(M2 + (size_t)M2_WORDS * 4);    // 0.19 MB

  uint32_t dk1a, dk1b, dk2a, dk2b;
  threefry2x32(0u, 42u, 0u, 0u, &dk1a, &dk1b);
  threefry2x32(0u, 42u, 0u, 1u, &dk2a, &dk2b);

  k_prep<<<3248, 256, 0, stream>>>((uint32_t*)M1, (uint32_t*)M2, w_ih, Wb,
                                   dk1a, dk1b, dk2a, dk2b);
  k_main<<<BATCH, 512, 0, stream>>>(inputs, emb, Wb, b_ih, (const uint32_t*)M1,
                                    GI, w_hh, b_hh, M2, Hd, w_lin, b_lin, out);
}